// Round 7
// baseline (299.707 us; speedup 1.0000x reference)
//
#include <hip/hip_runtime.h>

constexpr int B  = 4;
constexpr int C  = 256;
constexpr int N  = 2304;   // 48*48
constexpr int NH = 8;
constexpr int DK = 32;     // C / NH

typedef short short8 __attribute__((ext_vector_type(8)));   // 8 bf16 (raw bits)
typedef float f32x4  __attribute__((ext_vector_type(4)));

// f32 -> bf16 bits, round-to-nearest-even (proj epilogue)
static __device__ __forceinline__ ushort f2bf(float f) {
    union { float f; unsigned u; } v; v.f = f;
    return (ushort)((v.u + 0x7FFFu + ((v.u >> 16) & 1u)) >> 16);
}
// packed f32x2 -> bf16x2 (hardware RTNE)
static __device__ __forceinline__ unsigned cvtpk(float lo, float hi) {
    unsigned r;
    asm("v_cvt_pk_bf16_f32 %0, %1, %2" : "=v"(r) : "v"(lo), "v"(hi));
    return r;
}

// ---------------------------------------------------------------------------
// Projection GEMM: q/k -> [b][n][o] (o contig, bf16); v -> TRANSPOSED
// vT[b][o][n] (n contig) so attention's PV B-fragments are direct 16B loads.
// q scaled by log2(e)/sqrt(d_k) (exp2-domain attention).
// ---------------------------------------------------------------------------
__global__ __launch_bounds__(256) void proj_kernel(
    const float* __restrict__ x,
    const float* __restrict__ wq,
    const float* __restrict__ wk,
    const float* __restrict__ wv,
    ushort* __restrict__ ws,
    int bfix, size_t matStride, size_t batchStride)
{
    const int tile = blockIdx.x;
    const int mat  = blockIdx.y;
    const int b    = (bfix >= 0) ? bfix : (int)blockIdx.z;
    const int n0 = (tile % (N / 64)) * 64;
    const int o0 = (tile / (N / 64)) * 64;

    const float* w = (mat == 0) ? wq : (mat == 1) ? wk : wv;
    ushort* out = ws + (size_t)mat * matStride + (size_t)b * batchStride;
    const float* xb = x + (size_t)b * C * N;

    __shared__ float xs[16][64];
    __shared__ float wt[64][17];

    const int tid = threadIdx.x;
    const int tx = tid & 15;
    const int ty = tid >> 4;

    float acc[4][4] = {};

    for (int k0 = 0; k0 < C; k0 += 16) {
        {
            const int kk  = tid >> 4;
            const int nn4 = tid & 15;
            float4 v = *reinterpret_cast<const float4*>(xb + (size_t)(k0 + kk) * N + n0 + nn4 * 4);
            *reinterpret_cast<float4*>(&xs[kk][nn4 * 4]) = v;
        }
        {
            const int oo = tid >> 2;
            const int k4 = tid & 3;
            float4 v = *reinterpret_cast<const float4*>(w + (size_t)(o0 + oo) * C + k0 + k4 * 4);
            wt[oo][k4 * 4 + 0] = v.x;
            wt[oo][k4 * 4 + 1] = v.y;
            wt[oo][k4 * 4 + 2] = v.z;
            wt[oo][k4 * 4 + 3] = v.w;
        }
        __syncthreads();

        #pragma unroll
        for (int kk = 0; kk < 16; ++kk) {
            float4 a = *reinterpret_cast<const float4*>(&xs[kk][tx * 4]);
            float av[4] = {a.x, a.y, a.z, a.w};
            float bv[4];
            #pragma unroll
            for (int jo = 0; jo < 4; ++jo) bv[jo] = wt[ty * 4 + jo][kk];
            #pragma unroll
            for (int jo = 0; jo < 4; ++jo)
                #pragma unroll
                for (int jn = 0; jn < 4; ++jn)
                    acc[jo][jn] = fmaf(bv[jo], av[jn], acc[jo][jn]);
        }
        __syncthreads();
    }

    if (mat == 2) {
        // vT[o][n]: per jo, 4 consecutive n as ushort4
        #pragma unroll
        for (int jo = 0; jo < 4; ++jo) {
            ushort4 w4 = make_ushort4(f2bf(acc[jo][0]), f2bf(acc[jo][1]),
                                      f2bf(acc[jo][2]), f2bf(acc[jo][3]));
            *reinterpret_cast<ushort4*>(out + (size_t)(o0 + ty * 4 + jo) * N + n0 + tx * 4) = w4;
        }
    } else {
        const float sc = (mat == 0) ? 0.25503450535f : 1.0f;  // log2(e)/sqrt(32)
        #pragma unroll
        for (int jn = 0; jn < 4; ++jn) {
            ushort4 w4 = make_ushort4(f2bf(acc[0][jn] * sc), f2bf(acc[1][jn] * sc),
                                      f2bf(acc[2][jn] * sc), f2bf(acc[3][jn] * sc));
            *reinterpret_cast<ushort4*>(out + (size_t)(n0 + tx * 4 + jn) * C + o0 + ty * 4) = w4;
        }
    }
}

// ---------------------------------------------------------------------------
// MFMA flash attention, exp2 domain, NO main-loop LDS staging / barriers.
// Block = 128 thr = 2 waves, wave owns 16 q-rows. K-frags and V^T-frags are
// direct coalesced global loads (L2/L1-resident), register double-buffered
// one tile ahead. P goes through wave-private LDS scratch (no sync needed).
// Defer-max softmax; epilogue transposes O via LDS for coalesced writes.
// ---------------------------------------------------------------------------
__global__ __launch_bounds__(128) void attn_kernel(
    const ushort* __restrict__ ws,
    const float* __restrict__ x,
    float* __restrict__ out,
    int bfix, size_t matStride, size_t batchStride, int ppx)
{
    __shared__ __align__(16) char smem[9216];   // [0,4608): P scratch; [4608,9216): Ost

    const int tid = threadIdx.x;
    const int wq  = tid >> 6;        // wave 0..1
    const int l   = tid & 63;
    const int lq  = l & 15;
    const int g   = l >> 4;

    ushort* Pl = (ushort*)smem + wq * 1152;     // wave's P [16][72] bf16
    float*  Ost = (float*)(smem + 4608);        // [32][36] f32

    // XCD-affine: gid&7 = XCD; each XCD owns whole (b,h) pairs.
    const int gid  = blockIdx.x;
    const int xcd  = gid & 7;
    const int loc  = gid >> 3;
    const int pair = xcd * ppx + loc / 72;
    const int qt   = loc % 72;
    const int h    = pair & 7;
    const int b    = (bfix >= 0) ? bfix : (pair >> 3);
    const int n0   = qt * 32;

    const ushort* qbh = ws + (size_t)b * batchStride + h * DK;
    const ushort* kbh = ws + matStride + (size_t)b * batchStride + h * DK;
    const ushort* vth = ws + 2 * matStride + (size_t)b * batchStride + (size_t)h * DK * N;

    // Q fragment: lane supplies Q[q=lq][d = 8g..8g+7]
    short8 qf = *reinterpret_cast<const short8*>(
        qbh + (size_t)(n0 + wq * 16 + lq) * C + 8 * g);

    f32x4 acc0 = {0.f, 0.f, 0.f, 0.f};
    f32x4 acc1 = {0.f, 0.f, 0.f, 0.f};
    float m = -1e30f, lsum = 0.f;

    // Direct-frag tile load: K[lq+16u][8g..+7], V^T[lq(+16)][32w+8g..+7]
    #define LOADT(KA0,KA1,KA2,KA3,VA0,VA1,VA2,VA3,TT) {                         \
        const ushort* kt_ = kbh + (size_t)(TT) * 64 * C;                        \
        const ushort* vt_ = vth + (TT) * 64;                                    \
        KA0 = *reinterpret_cast<const short8*>(kt_ + (lq     ) * C + 8 * g);    \
        KA1 = *reinterpret_cast<const short8*>(kt_ + (lq + 16) * C + 8 * g);    \
        KA2 = *reinterpret_cast<const short8*>(kt_ + (lq + 32) * C + 8 * g);    \
        KA3 = *reinterpret_cast<const short8*>(kt_ + (lq + 48) * C + 8 * g);    \
        VA0 = *reinterpret_cast<const short8*>(vt_ + (size_t)(lq     ) * N + 8 * g);      \
        VA1 = *reinterpret_cast<const short8*>(vt_ + (size_t)(lq + 16) * N + 8 * g);      \
        VA2 = *reinterpret_cast<const short8*>(vt_ + (size_t)(lq     ) * N + 8 * g + 32); \
        VA3 = *reinterpret_cast<const short8*>(vt_ + (size_t)(lq + 16) * N + 8 * g + 32); \
    }

    #define COMPUTE(KA0,KA1,KA2,KA3,VA0,VA1,VA2,VA3) {                          \
        f32x4 z = {0.f, 0.f, 0.f, 0.f};                                         \
        f32x4 s0, s1, s2, s3;                                                   \
        __builtin_amdgcn_s_setprio(1);                                          \
        s0 = __builtin_amdgcn_mfma_f32_16x16x32_bf16(KA0, qf, z, 0, 0, 0);      \
        s1 = __builtin_amdgcn_mfma_f32_16x16x32_bf16(KA1, qf, z, 0, 0, 0);      \
        s2 = __builtin_amdgcn_mfma_f32_16x16x32_bf16(KA2, qf, z, 0, 0, 0);      \
        s3 = __builtin_amdgcn_mfma_f32_16x16x32_bf16(KA3, qf, z, 0, 0, 0);      \
        __builtin_amdgcn_s_setprio(0);                                          \
        float mxl = s0[0];                                                      \
        _Pragma("unroll") for (int r = 0; r < 4; ++r) {                         \
            mxl = fmaxf(mxl, s0[r]); mxl = fmaxf(mxl, s1[r]);                   \
            mxl = fmaxf(mxl, s2[r]); mxl = fmaxf(mxl, s3[r]);                   \
        }                                                                       \
        if (!__all(mxl <= m + 8.0f)) {                                          \
            float mx = fmaxf(mxl, __shfl_xor(mxl, 16));                         \
            mx = fmaxf(mx, __shfl_xor(mx, 32));                                 \
            float nm = fmaxf(m, mx);                                            \
            float corr = exp2f(m - nm);                                         \
            m = nm; lsum *= corr;                                               \
            float cw0 = __shfl(corr, 4 * g + 0);                                \
            float cw1 = __shfl(corr, 4 * g + 1);                                \
            float cw2 = __shfl(corr, 4 * g + 2);                                \
            float cw3 = __shfl(corr, 4 * g + 3);                                \
            acc0[0] *= cw0; acc0[1] *= cw1; acc0[2] *= cw2; acc0[3] *= cw3;     \
            acc1[0] *= cw0; acc1[1] *= cw1; acc1[2] *= cw2; acc1[3] *= cw3;     \
        }                                                                       \
        float ps = 0.f;                                                         \
        uint2 pw0, pw1, pw2, pw3;                                               \
        {                                                                       \
            float p0 = exp2f(s0[0] - m), p1 = exp2f(s0[1] - m);                 \
            float p2 = exp2f(s0[2] - m), p3 = exp2f(s0[3] - m);                 \
            ps += (p0 + p1) + (p2 + p3);                                        \
            pw0.x = cvtpk(p0, p1); pw0.y = cvtpk(p2, p3);                       \
        }                                                                       \
        {                                                                       \
            float p0 = exp2f(s1[0] - m), p1 = exp2f(s1[1] - m);                 \
            float p2 = exp2f(s1[2] - m), p3 = exp2f(s1[3] - m);                 \
            ps += (p0 + p1) + (p2 + p3);                                        \
            pw1.x = cvtpk(p0, p1); pw1.y = cvtpk(p2, p3);                       \
        }                                                                       \
        {                                                                       \
            float p0 = exp2f(s2[0] - m), p1 = exp2f(s2[1] - m);                 \
            float p2 = exp2f(s2[2] - m), p3 = exp2f(s2[3] - m);                 \
            ps += (p0 + p1) + (p2 + p3);                                        \
            pw2.x = cvtpk(p0, p1); pw2.y = cvtpk(p2, p3);                       \
        }                                                                       \
        {                                                                       \
            float p0 = exp2f(s3[0] - m), p1 = exp2f(s3[1] - m);                 \
            float p2 = exp2f(s3[2] - m), p3 = exp2f(s3[3] - m);                 \
            ps += (p0 + p1) + (p2 + p3);                                        \
            pw3.x = cvtpk(p0, p1); pw3.y = cvtpk(p2, p3);                       \
        }                                                                       \
        lsum += ps;                                                             \
        *reinterpret_cast<uint2*>(Pl + lq * 72 + 4 * g     ) = pw0;             \
        *reinterpret_cast<uint2*>(Pl + lq * 72 + 4 * g + 16) = pw1;             \
        *reinterpret_cast<uint2*>(Pl + lq * 72 + 4 * g + 32) = pw2;             \
        *reinterpret_cast<uint2*>(Pl + lq * 72 + 4 * g + 48) = pw3;             \
        short8 pf0 = *reinterpret_cast<const short8*>(Pl + lq * 72 + 8 * g);    \
        short8 pf1 = *reinterpret_cast<const short8*>(Pl + lq * 72 + 32 + 8 * g); \
        __builtin_amdgcn_s_setprio(1);                                          \
        acc0 = __builtin_amdgcn_mfma_f32_16x16x32_bf16(pf0, VA0, acc0, 0, 0, 0); \
        acc1 = __builtin_amdgcn_mfma_f32_16x16x32_bf16(pf0, VA1, acc1, 0, 0, 0); \
        acc0 = __builtin_amdgcn_mfma_f32_16x16x32_bf16(pf1, VA2, acc0, 0, 0, 0); \
        acc1 = __builtin_amdgcn_mfma_f32_16x16x32_bf16(pf1, VA3, acc1, 0, 0, 0); \
        __builtin_amdgcn_s_setprio(0);                                          \
    }

    short8 kA0, kA1, kA2, kA3, vA0, vA1, vA2, vA3;
    short8 kB0, kB1, kB2, kB3, vB0, vB1, vB2, vB3;

    LOADT(kA0,kA1,kA2,kA3, vA0,vA1,vA2,vA3, 0);

    for (int t = 0; t < N / 64; t += 2) {
        LOADT(kB0,kB1,kB2,kB3, vB0,vB1,vB2,vB3, t + 1);
        COMPUTE(kA0,kA1,kA2,kA3, vA0,vA1,vA2,vA3);
        const int t2 = (t + 2 == N / 64) ? 0 : t + 2;   // clamp (harmless reload)
        LOADT(kA0,kA1,kA2,kA3, vA0,vA1,vA2,vA3, t2);
        COMPUTE(kB0,kB1,kB2,kB3, vB0,vB1,vB2,vB3);
    }
    #undef LOADT
    #undef COMPUTE

    // ---- epilogue: reduce lsum, normalize, transpose via LDS, residual add
    lsum += __shfl_xor(lsum, 16);
    lsum += __shfl_xor(lsum, 32);
    const float iv = 1.0f / lsum;
    float iw0 = __shfl(iv, 4 * g + 0);
    float iw1 = __shfl(iv, 4 * g + 1);
    float iw2 = __shfl(iv, 4 * g + 2);
    float iw3 = __shfl(iv, 4 * g + 3);

    Ost[(lq +  0) * 36 + wq * 16 + 4 * g + 0] = acc0[0] * iw0;
    Ost[(lq +  0) * 36 + wq * 16 + 4 * g + 1] = acc0[1] * iw1;
    Ost[(lq +  0) * 36 + wq * 16 + 4 * g + 2] = acc0[2] * iw2;
    Ost[(lq +  0) * 36 + wq * 16 + 4 * g + 3] = acc0[3] * iw3;
    Ost[(lq + 16) * 36 + wq * 16 + 4 * g + 0] = acc1[0] * iw0;
    Ost[(lq + 16) * 36 + wq * 16 + 4 * g + 1] = acc1[1] * iw1;
    Ost[(lq + 16) * 36 + wq * 16 + 4 * g + 2] = acc1[2] * iw2;
    Ost[(lq + 16) * 36 + wq * 16 + 4 * g + 3] = acc1[3] * iw3;
    __syncthreads();

    {
        const int d  = tid >> 2;          // 0..31
        const int nn = (tid & 3) * 8;     // 0,8,16,24
        const size_t go = ((size_t)b * C + h * DK + d) * (size_t)N + n0 + nn;
        float4 o1 = *reinterpret_cast<float4*>(Ost + d * 36 + nn);
        float4 o2 = *reinterpret_cast<float4*>(Ost + d * 36 + nn + 4);
        float4 x1 = *reinterpret_cast<const float4*>(x + go);
        float4 x2 = *reinterpret_cast<const float4*>(x + go + 4);
        *reinterpret_cast<float4*>(out + go)     = make_float4(o1.x + x1.x, o1.y + x1.y, o1.z + x1.z, o1.w + x1.w);
        *reinterpret_cast<float4*>(out + go + 4) = make_float4(o2.x + x2.x, o2.y + x2.y, o2.z + x2.z, o2.w + x2.w);
    }
}

extern "C" void kernel_launch(void* const* d_in, const int* in_sizes, int n_in,
                              void* d_out, int out_size, void* d_ws, size_t ws_size,
                              hipStream_t stream) {
    const float* x  = (const float*)d_in[0];
    const float* wq = (const float*)d_in[1];
    const float* wk = (const float*)d_in[2];
    const float* wv = (const float*)d_in[3];
    float* out = (float*)d_out;
    ushort* ws = (ushort*)d_ws;

    const size_t NC = (size_t)N * C;
    const size_t needFull = 3 * (size_t)B * NC * sizeof(ushort);   // 14.2 MB

    if (ws_size >= needFull) {
        proj_kernel<<<dim3((N / 64) * (C / 64), 3, B), 256, 0, stream>>>(
            x, wq, wk, wv, ws, -1, (size_t)B * NC, NC);
        attn_kernel<<<dim3(72 * NH * B), 128, 0, stream>>>(
            ws, x, out, -1, (size_t)B * NC, NC, 4);
    } else {
        // per-batch fallback (3.5 MB): proj_b -> attn_b serialized on stream
        for (int b = 0; b < B; ++b) {
            proj_kernel<<<dim3((N / 64) * (C / 64), 3, 1), 256, 0, stream>>>(
                x, wq, wk, wv, ws, b, NC, 0);
            attn_kernel<<<dim3(72 * NH), 128, 0, stream>>>(
                ws, x, out, b, NC, 0, 1);
        }
    }
}

// Round 11
// 221.329 us; speedup vs baseline: 1.3541x; 1.3541x over previous
//
#include <hip/hip_runtime.h>

constexpr int B  = 4;
constexpr int C  = 256;
constexpr int N  = 2304;   // 48*48
constexpr int NH = 8;
constexpr int DK = 32;     // C / NH

typedef short short8 __attribute__((ext_vector_type(8)));   // 8 bf16 (raw bits)
typedef float f32x4  __attribute__((ext_vector_type(4)));

// f32 -> bf16 bits, round-to-nearest-even (proj epilogue)
static __device__ __forceinline__ ushort f2bf(float f) {
    union { float f; unsigned u; } v; v.f = f;
    return (ushort)((v.u + 0x7FFFu + ((v.u >> 16) & 1u)) >> 16);
}
// packed f32x2 -> bf16x2 (hardware RTNE)
static __device__ __forceinline__ unsigned cvtpk(float lo, float hi) {
    unsigned r;
    asm("v_cvt_pk_bf16_f32 %0, %1, %2" : "=v"(r) : "v"(lo), "v"(hi));
    return r;
}

// ---------------------------------------------------------------------------
// Projection GEMM, rewritten for FMA density: q/k/v[b][n][o] = sum_c
// x[b][c][n]*w[o][c], bf16 out. Tile 128n x 128o, 256 thr, 8x8 out/thread:
// 64 FMA per 4 b128 LDS reads per kk (VALU-bound). W staged TRANSPOSED in
// LDS (wtT[kk][oo]) so B-operands are float4 reads. Stores: tid&15 = o-dim
// fast -> contiguous 256B runs. q scaled by log2(e)/sqrt(d_k).
// ---------------------------------------------------------------------------
__global__ __launch_bounds__(256) void proj_kernel(
    const float* __restrict__ x,
    const float* __restrict__ wq,
    const float* __restrict__ wk,
    const float* __restrict__ wv,
    ushort* __restrict__ ws,
    int bfix, size_t matStride, size_t batchStride)
{
    const int mat = blockIdx.y;
    const int b   = (bfix >= 0) ? bfix : (int)blockIdx.z;
    const int n0  = (blockIdx.x % 18) * 128;
    const int o0  = (blockIdx.x / 18) * 128;

    const float* w = (mat == 0) ? wq : (mat == 1) ? wk : wv;
    ushort* out = ws + (size_t)mat * matStride + (size_t)b * batchStride;
    const float* xb = x + (size_t)b * C * N;

    __shared__ float xs[16][128];     // [kk][n]
    __shared__ float wtT[16][132];    // [kk][o], transposed W, padded

    const int tid = threadIdx.x;
    const int tx = tid >> 4;          // n-octet 0..15
    const int ty = tid & 15;          // o-octet 0..15 (fast -> coalesced stores)

    float acc[8][8] = {};             // acc[jn][jo]

    for (int k0 = 0; k0 < C; k0 += 16) {
        {   // stage X tile: 16x128 f32; 2 float4/thread, 256B runs
            const int kk  = tid >> 4;
            const int nn4 = tid & 15;
            *reinterpret_cast<float4*>(&xs[kk][nn4 * 4]) =
                *reinterpret_cast<const float4*>(xb + (size_t)(k0 + kk) * N + n0 + nn4 * 4);
            *reinterpret_cast<float4*>(&xs[kk][64 + nn4 * 4]) =
                *reinterpret_cast<const float4*>(xb + (size_t)(k0 + kk) * N + n0 + 64 + nn4 * 4);
        }
        {   // stage W transposed: thread (oo=tid>>1, kh=tid&1) reads 2 float4,
            // scatters 8 scalars into wtT[kk][oo]
            const int oo = tid >> 1;
            const int kh = tid & 1;
            float4 wa = *reinterpret_cast<const float4*>(w + (size_t)(o0 + oo) * C + k0 + kh * 4);
            float4 wb = *reinterpret_cast<const float4*>(w + (size_t)(o0 + oo) * C + k0 + kh * 4 + 8);
            wtT[kh * 4 + 0][oo] = wa.x;
            wtT[kh * 4 + 1][oo] = wa.y;
            wtT[kh * 4 + 2][oo] = wa.z;
            wtT[kh * 4 + 3][oo] = wa.w;
            wtT[kh * 4 + 8][oo] = wb.x;
            wtT[kh * 4 + 9][oo] = wb.y;
            wtT[kh * 4 + 10][oo] = wb.z;
            wtT[kh * 4 + 11][oo] = wb.w;
        }
        __syncthreads();

        #pragma unroll
        for (int kk = 0; kk < 16; ++kk) {
            float4 a0 = *reinterpret_cast<const float4*>(&xs[kk][tx * 8]);
            float4 a1 = *reinterpret_cast<const float4*>(&xs[kk][tx * 8 + 4]);
            float4 b0 = *reinterpret_cast<const float4*>(&wtT[kk][ty * 8]);
            float4 b1 = *reinterpret_cast<const float4*>(&wtT[kk][ty * 8 + 4]);
            float av[8] = {a0.x, a0.y, a0.z, a0.w, a1.x, a1.y, a1.z, a1.w};
            float bv[8] = {b0.x, b0.y, b0.z, b0.w, b1.x, b1.y, b1.z, b1.w};
            #pragma unroll
            for (int jn = 0; jn < 8; ++jn)
                #pragma unroll
                for (int jo = 0; jo < 8; ++jo)
                    acc[jn][jo] = fmaf(av[jn], bv[jo], acc[jn][jo]);
        }
        __syncthreads();
    }

    // epilogue: bf16 pack, one ushort8 (16B) per jn row; lanes ty fast ->
    // 16 x 16B = contiguous 256B per (tx, jn)
    const float sc = (mat == 0) ? 0.25503450535f : 1.0f;  // log2(e)/sqrt(32)
    #pragma unroll
    for (int jn = 0; jn < 8; ++jn) {
        unsigned pk[4];
        #pragma unroll
        for (int p = 0; p < 4; ++p)
            pk[p] = cvtpk(acc[jn][2 * p] * sc, acc[jn][2 * p + 1] * sc);
        *reinterpret_cast<uint4*>(out + (size_t)(n0 + tx * 8 + jn) * C + o0 + ty * 8) =
            make_uint4(pk[0], pk[1], pk[2], pk[3]);
    }
}

// ---------------------------------------------------------------------------
// MFMA flash attention (VERIFIED R6 structure, byte-identical): 16x16x32,
// swapped QK^T, exp2 domain, defer-max, cvt_pk, P via wave-private LDS,
// reg-staged K/V tiles, 128 thr = 2 waves.
// ---------------------------------------------------------------------------
__global__ __launch_bounds__(128) void attn_kernel(
    const ushort* __restrict__ ws,
    const float* __restrict__ x,
    float* __restrict__ out,
    int bfix, size_t matStride, size_t batchStride, int ppx)
{
    __shared__ __align__(16) char smem[14336];
    ushort* Ks  = (ushort*)smem;             // [64][40] bf16
    ushort* Vt  = (ushort*)(smem + 5120);    // [32][72] bf16 (V transposed)
    float*  Ost = (float*) smem;             // [32][36] f32 (epilogue reuse)

    const int tid = threadIdx.x;
    const int wq  = tid >> 6;        // wave 0..1
    const int l   = tid & 63;
    const int lq  = l & 15;
    const int g   = l >> 4;

    ushort* Pl = (ushort*)(smem + 9728) + wq * 1152;   // wave's P [16][72]

    // XCD-affine: gid&7 = XCD; each XCD owns whole (b,h) pairs.
    const int gid  = blockIdx.x;
    const int xcd  = gid & 7;
    const int loc  = gid >> 3;
    const int pair = xcd * ppx + loc / 72;
    const int qt   = loc % 72;
    const int h    = pair & 7;
    const int b    = (bfix >= 0) ? bfix : (pair >> 3);
    const int n0   = qt * 32;

    const ushort* qb = ws + (size_t)b * batchStride;
    const ushort* kb = qb + matStride;
    const ushort* vb = qb + 2 * matStride;

    // Q fragment: lane supplies Q[q=lq][d = 8g..8g+7]
    short8 qf = *reinterpret_cast<const short8*>(
        qb + (size_t)(n0 + wq * 16 + lq) * C + h * DK + 8 * g);

    f32x4 acc0 = {0.f, 0.f, 0.f, 0.f};
    f32x4 acc1 = {0.f, 0.f, 0.f, 0.f};
    float m = -1e30f, lsum = 0.f;   // lsum: per-lane partial (reduced at end)

    // staging decomposition (128 threads)
    const int kr = tid >> 2, kc = tid & 3;      // K: rows kr, kr+32; 16B chunk kc
    const int vp = tid & 31, vd = tid >> 5;     // V: key-pair vp, d-groups vd, vd+4

    short8  kreg0, kreg1;
    ushort4 va0, vc0, va1, vc1;

    #define LOAD_TILE(m0_)                                                          \
        {                                                                           \
            const int m0i = (m0_);                                                  \
            kreg0 = *reinterpret_cast<const short8*>(kb + (size_t)(m0i + kr) * C + h * DK + kc * 8);        \
            kreg1 = *reinterpret_cast<const short8*>(kb + (size_t)(m0i + 32 + kr) * C + h * DK + kc * 8);   \
            const ushort* v0 = vb + (size_t)(m0i + 2 * vp) * C + h * DK + vd * 4;   \
            va0 = *reinterpret_cast<const ushort4*>(v0);                            \
            vc0 = *reinterpret_cast<const ushort4*>(v0 + C);                        \
            va1 = *reinterpret_cast<const ushort4*>(v0 + 16);                       \
            vc1 = *reinterpret_cast<const ushort4*>(v0 + C + 16);                   \
        }

    LOAD_TILE(0);

    for (int t = 0; t < N / 64; ++t) {
        // ---- write staged tile to LDS (implicit vmcnt wait on regs)
        *reinterpret_cast<short8*>(Ks + kr * 40 + kc * 8) = kreg0;
        *reinterpret_cast<short8*>(Ks + (kr + 32) * 40 + kc * 8) = kreg1;
        {
            unsigned p0 = (unsigned)va0.x | ((unsigned)vc0.x << 16);
            unsigned p1 = (unsigned)va0.y | ((unsigned)vc0.y << 16);
            unsigned p2 = (unsigned)va0.z | ((unsigned)vc0.z << 16);
            unsigned p3 = (unsigned)va0.w | ((unsigned)vc0.w << 16);
            *reinterpret_cast<unsigned*>(Vt + (vd * 4 + 0) * 72 + 2 * vp) = p0;
            *reinterpret_cast<unsigned*>(Vt + (vd * 4 + 1) * 72 + 2 * vp) = p1;
            *reinterpret_cast<unsigned*>(Vt + (vd * 4 + 2) * 72 + 2 * vp) = p2;
            *reinterpret_cast<unsigned*>(Vt + (vd * 4 + 3) * 72 + 2 * vp) = p3;
            unsigned q0 = (unsigned)va1.x | ((unsigned)vc1.x << 16);
            unsigned q1 = (unsigned)va1.y | ((unsigned)vc1.y << 16);
            unsigned q2 = (unsigned)va1.z | ((unsigned)vc1.z << 16);
            unsigned q3 = (unsigned)va1.w | ((unsigned)vc1.w << 16);
            *reinterpret_cast<unsigned*>(Vt + (vd * 4 + 16) * 72 + 2 * vp) = q0;
            *reinterpret_cast<unsigned*>(Vt + (vd * 4 + 17) * 72 + 2 * vp) = q1;
            *reinterpret_cast<unsigned*>(Vt + (vd * 4 + 18) * 72 + 2 * vp) = q2;
            *reinterpret_cast<unsigned*>(Vt + (vd * 4 + 19) * 72 + 2 * vp) = q3;
        }
        __syncthreads();

        // ---- issue next tile's global loads (overlap with compute below)
        if (t < N / 64 - 1) LOAD_TILE((t + 1) * 64);

        // ---- QK^T (swapped): st[u][r] = S[key=16u+4g+r][q=lq]
        f32x4 st[4];
        __builtin_amdgcn_s_setprio(1);
        #pragma unroll
        for (int u = 0; u < 4; ++u) {
            short8 kf = *reinterpret_cast<const short8*>(Ks + (lq + 16 * u) * 40 + 8 * g);
            f32x4 z = {0.f, 0.f, 0.f, 0.f};
            st[u] = __builtin_amdgcn_mfma_f32_16x16x32_bf16(kf, qf, z, 0, 0, 0);
        }
        __builtin_amdgcn_s_setprio(0);

        // ---- online softmax, exp2 domain, defer-max
        float mxl = st[0][0];
        #pragma unroll
        for (int u = 0; u < 4; ++u)
            #pragma unroll
            for (int r = 0; r < 4; ++r) mxl = fmaxf(mxl, st[u][r]);

        if (!__all(mxl <= m + 8.0f)) {
            float mx = fmaxf(mxl, __shfl_xor(mxl, 16));
            mx = fmaxf(mx, __shfl_xor(mx, 32));
            float nm = fmaxf(m, mx);
            float corr = exp2f(m - nm);
            m = nm;
            lsum *= corr;
            float cw0 = __shfl(corr, 4 * g + 0);
            float cw1 = __shfl(corr, 4 * g + 1);
            float cw2 = __shfl(corr, 4 * g + 2);
            float cw3 = __shfl(corr, 4 * g + 3);
            acc0[0] *= cw0; acc0[1] *= cw1; acc0[2] *= cw2; acc0[3] *= cw3;
            acc1[0] *= cw0; acc1[1] *= cw1; acc1[2] *= cw2; acc1[3] *= cw3;
        }

        float ps = 0.f;
        uint2 pw[4];
        #pragma unroll
        for (int u = 0; u < 4; ++u) {
            float p0 = exp2f(st[u][0] - m);
            float p1 = exp2f(st[u][1] - m);
            float p2 = exp2f(st[u][2] - m);
            float p3 = exp2f(st[u][3] - m);
            ps += (p0 + p1) + (p2 + p3);
            pw[u].x = cvtpk(p0, p1);
            pw[u].y = cvtpk(p2, p3);
        }
        lsum += ps;

        #pragma unroll
        for (int u = 0; u < 4; ++u)
            *reinterpret_cast<uint2*>(Pl + lq * 72 + 4 * g + 16 * u) = pw[u];

        // ---- PV: O[q=4g+r][d=lq(+16)]
        short8 pf0 = *reinterpret_cast<const short8*>(Pl + lq * 72 + 8 * g);
        short8 pf1 = *reinterpret_cast<const short8*>(Pl + lq * 72 + 32 + 8 * g);
        __builtin_amdgcn_s_setprio(1);
        #pragma unroll
        for (int k2 = 0; k2 < 2; ++k2) {
            short8 pf = k2 ? pf1 : pf0;
            short8 vf0 = *reinterpret_cast<const short8*>(Vt + lq * 72 + 32 * k2 + 8 * g);
            short8 vf1 = *reinterpret_cast<const short8*>(Vt + (lq + 16) * 72 + 32 * k2 + 8 * g);
            acc0 = __builtin_amdgcn_mfma_f32_16x16x32_bf16(pf, vf0, acc0, 0, 0, 0);
            acc1 = __builtin_amdgcn_mfma_f32_16x16x32_bf16(pf, vf1, acc1, 0, 0, 0);
        }
        __builtin_amdgcn_s_setprio(0);
        __syncthreads();
    }

    // ---- epilogue: reduce lsum, normalize, transpose via LDS, residual add
    lsum += __shfl_xor(lsum, 16);
    lsum += __shfl_xor(lsum, 32);
    const float iv = 1.0f / lsum;
    float iw0 = __shfl(iv, 4 * g + 0);
    float iw1 = __shfl(iv, 4 * g + 1);
    float iw2 = __shfl(iv, 4 * g + 2);
    float iw3 = __shfl(iv, 4 * g + 3);

    Ost[(lq +  0) * 36 + wq * 16 + 4 * g + 0] = acc0[0] * iw0;
    Ost[(lq +  0) * 36 + wq * 16 + 4 * g + 1] = acc0[1] * iw1;
    Ost[(lq +  0) * 36 + wq * 16 + 4 * g + 2] = acc0[2] * iw2;
    Ost[(lq +  0) * 36 + wq * 16 + 4 * g + 3] = acc0[3] * iw3;
    Ost[(lq + 16) * 36 + wq * 16 + 4 * g + 0] = acc1[0] * iw0;
    Ost[(lq + 16) * 36 + wq * 16 + 4 * g + 1] = acc1[1] * iw1;
    Ost[(lq + 16) * 36 + wq * 16 + 4 * g + 2] = acc1[2] * iw2;
    Ost[(lq + 16) * 36 + wq * 16 + 4 * g + 3] = acc1[3] * iw3;
    __syncthreads();

    {
        const int d  = tid >> 2;          // 0..31
        const int nn = (tid & 3) * 8;     // 0,8,16,24
        const size_t go = ((size_t)b * C + h * DK + d) * (size_t)N + n0 + nn;
        float4 o1 = *reinterpret_cast<float4*>(Ost + d * 36 + nn);
        float4 o2 = *reinterpret_cast<float4*>(Ost + d * 36 + nn + 4);
        float4 x1 = *reinterpret_cast<const float4*>(x + go);
        float4 x2 = *reinterpret_cast<const float4*>(x + go + 4);
        *reinterpret_cast<float4*>(out + go)     = make_float4(o1.x + x1.x, o1.y + x1.y, o1.z + x1.z, o1.w + x1.w);
        *reinterpret_cast<float4*>(out + go + 4) = make_float4(o2.x + x2.x, o2.y + x2.y, o2.z + x2.z, o2.w + x2.w);
    }
}

extern "C" void kernel_launch(void* const* d_in, const int* in_sizes, int n_in,
                              void* d_out, int out_size, void* d_ws, size_t ws_size,
                              hipStream_t stream) {
    const float* x  = (const float*)d_in[0];
    const float* wq = (const float*)d_in[1];
    const float* wk = (const float*)d_in[2];
    const float* wv = (const float*)d_in[3];
    float* out = (float*)d_out;
    ushort* ws = (ushort*)d_ws;

    const size_t NC = (size_t)N * C;
    const size_t needFull = 3 * (size_t)B * NC * sizeof(ushort);   // 14.2 MB

    if (ws_size >= needFull) {
        proj_kernel<<<dim3(18 * 2, 3, B), 256, 0, stream>>>(
            x, wq, wk, wv, ws, -1, (size_t)B * NC, NC);
        attn_kernel<<<dim3(72 * NH * B), 128, 0, stream>>>(
            ws, x, out, -1, (size_t)B * NC, NC, 4);
    } else {
        // per-batch fallback (3.5 MB): proj_b -> attn_b serialized on stream
        for (int b = 0; b < B; ++b) {
            proj_kernel<<<dim3(18 * 2, 3, 1), 256, 0, stream>>>(
                x, wq, wk, wv, ws, b, NC, 0);
            attn_kernel<<<dim3(72 * NH), 128, 0, stream>>>(
                ws, x, out, b, NC, 0, 1);
        }
    }
}

// Round 12
// 204.437 us; speedup vs baseline: 1.4660x; 1.0826x over previous
//
#include <hip/hip_runtime.h>

constexpr int B  = 4;
constexpr int C  = 256;
constexpr int N  = 2304;   // 48*48
constexpr int NH = 8;
constexpr int DK = 32;     // C / NH

typedef short short8 __attribute__((ext_vector_type(8)));   // 8 bf16 (raw bits)
typedef float f32x4  __attribute__((ext_vector_type(4)));

// packed f32x2 -> bf16x2 (hardware RTNE)
static __device__ __forceinline__ unsigned cvtpk(float lo, float hi) {
    unsigned r;
    asm("v_cvt_pk_bf16_f32 %0, %1, %2" : "=v"(r) : "v"(lo), "v"(hi));
    return r;
}

// ---------------------------------------------------------------------------
// Projection GEMM (unchanged from R11): 128n x 128o tile, 8x8/thread,
// W transposed in LDS, bf16 out; q scaled by log2(e)/sqrt(d_k).
// ---------------------------------------------------------------------------
__global__ __launch_bounds__(256) void proj_kernel(
    const float* __restrict__ x,
    const float* __restrict__ wq,
    const float* __restrict__ wk,
    const float* __restrict__ wv,
    ushort* __restrict__ ws,
    int bfix, size_t matStride, size_t batchStride)
{
    const int mat = blockIdx.y;
    const int b   = (bfix >= 0) ? bfix : (int)blockIdx.z;
    const int n0  = (blockIdx.x % 18) * 128;
    const int o0  = (blockIdx.x / 18) * 128;

    const float* w = (mat == 0) ? wq : (mat == 1) ? wk : wv;
    ushort* out = ws + (size_t)mat * matStride + (size_t)b * batchStride;
    const float* xb = x + (size_t)b * C * N;

    __shared__ float xs[16][128];
    __shared__ float wtT[16][132];

    const int tid = threadIdx.x;
    const int tx = tid >> 4;
    const int ty = tid & 15;

    float acc[8][8] = {};

    for (int k0 = 0; k0 < C; k0 += 16) {
        {
            const int kk  = tid >> 4;
            const int nn4 = tid & 15;
            *reinterpret_cast<float4*>(&xs[kk][nn4 * 4]) =
                *reinterpret_cast<const float4*>(xb + (size_t)(k0 + kk) * N + n0 + nn4 * 4);
            *reinterpret_cast<float4*>(&xs[kk][64 + nn4 * 4]) =
                *reinterpret_cast<const float4*>(xb + (size_t)(k0 + kk) * N + n0 + 64 + nn4 * 4);
        }
        {
            const int oo = tid >> 1;
            const int kh = tid & 1;
            float4 wa = *reinterpret_cast<const float4*>(w + (size_t)(o0 + oo) * C + k0 + kh * 4);
            float4 wb = *reinterpret_cast<const float4*>(w + (size_t)(o0 + oo) * C + k0 + kh * 4 + 8);
            wtT[kh * 4 + 0][oo] = wa.x;
            wtT[kh * 4 + 1][oo] = wa.y;
            wtT[kh * 4 + 2][oo] = wa.z;
            wtT[kh * 4 + 3][oo] = wa.w;
            wtT[kh * 4 + 8][oo] = wb.x;
            wtT[kh * 4 + 9][oo] = wb.y;
            wtT[kh * 4 + 10][oo] = wb.z;
            wtT[kh * 4 + 11][oo] = wb.w;
        }
        __syncthreads();

        #pragma unroll
        for (int kk = 0; kk < 16; ++kk) {
            float4 a0 = *reinterpret_cast<const float4*>(&xs[kk][tx * 8]);
            float4 a1 = *reinterpret_cast<const float4*>(&xs[kk][tx * 8 + 4]);
            float4 b0 = *reinterpret_cast<const float4*>(&wtT[kk][ty * 8]);
            float4 b1 = *reinterpret_cast<const float4*>(&wtT[kk][ty * 8 + 4]);
            float av[8] = {a0.x, a0.y, a0.z, a0.w, a1.x, a1.y, a1.z, a1.w};
            float bv[8] = {b0.x, b0.y, b0.z, b0.w, b1.x, b1.y, b1.z, b1.w};
            #pragma unroll
            for (int jn = 0; jn < 8; ++jn)
                #pragma unroll
                for (int jo = 0; jo < 8; ++jo)
                    acc[jn][jo] = fmaf(av[jn], bv[jo], acc[jn][jo]);
        }
        __syncthreads();
    }

    const float sc = (mat == 0) ? 0.25503450535f : 1.0f;  // log2(e)/sqrt(32)
    #pragma unroll
    for (int jn = 0; jn < 8; ++jn) {
        unsigned pk[4];
        #pragma unroll
        for (int p = 0; p < 4; ++p)
            pk[p] = cvtpk(acc[jn][2 * p] * sc, acc[jn][2 * p + 1] * sc);
        *reinterpret_cast<uint4*>(out + (size_t)(n0 + tx * 8 + jn) * C + o0 + ty * 8) =
            make_uint4(pk[0], pk[1], pk[2], pk[3]);
    }
}

// ---------------------------------------------------------------------------
// MFMA flash attention: verified R6 per-wave compute path, restructured to
// 8-wave blocks (512 thr) with SHARED K/V staging. Wave wq owns q-rows
// n0 + wq*16 .. +15 (QT=128/block, 18 blocks per (b,h)). Waves 0-3 stage K
// (R5 pattern: 1 b128/thread), waves 4-7 stage V-transposed (R5 pack
// pattern: 2 ushort4 reads -> 4 dword writes/thread). Staging cost per
// wave-iter drops ~8x; occupancy 2.25 -> 4.5 waves/SIMD.
// ---------------------------------------------------------------------------
__global__ __launch_bounds__(512) void attn_kernel(
    const ushort* __restrict__ ws,
    const float* __restrict__ x,
    float* __restrict__ out,
    int bfix, size_t matStride, size_t batchStride, int ppx)
{
    __shared__ __align__(16) char smem[28160];
    ushort* Ks  = (ushort*)smem;             // [64][40] bf16
    ushort* Vt  = (ushort*)(smem + 5120);    // [32][72] bf16 (V transposed)
    float*  Ost = (float*) smem;             // [32][132] f32 (epilogue overlay)

    const int tid = threadIdx.x;
    const int wq  = tid >> 6;        // wave 0..7
    const int l   = tid & 63;
    const int lq  = l & 15;
    const int g   = l >> 4;

    ushort* Pl = (ushort*)(smem + 9728) + wq * 1152;   // wave's P [16][72]

    // XCD-affine: gid&7 = XCD; each XCD owns whole (b,h) pairs. 18 q-tiles/(b,h).
    const int gid  = blockIdx.x;
    const int xcd  = gid & 7;
    const int loc  = gid >> 3;
    const int pair = xcd * ppx + loc / 18;
    const int qt   = loc % 18;
    const int h    = pair & 7;
    const int b    = (bfix >= 0) ? bfix : (pair >> 3);
    const int n0   = qt * 128;

    const ushort* qb = ws + (size_t)b * batchStride;
    const ushort* kb = qb + matStride;
    const ushort* vb = qb + 2 * matStride;

    // Q fragment: lane supplies Q[q = n0+wq*16+lq][d = 8g..8g+7]
    short8 qf = *reinterpret_cast<const short8*>(
        qb + (size_t)(n0 + wq * 16 + lq) * C + h * DK + 8 * g);

    f32x4 acc0 = {0.f, 0.f, 0.f, 0.f};
    f32x4 acc1 = {0.f, 0.f, 0.f, 0.f};
    float m = -1e30f, lsum = 0.f;

    // staging roles: waves 0-3 -> K (R5 pattern), waves 4-7 -> V (R5 pattern)
    const int kr = tid >> 2, kc = tid & 3;          // K: row kr (0..63), 16B chunk kc
    const int t2 = tid - 256;
    const int vp = t2 & 31, vd = t2 >> 5;           // V: key-pair vp, d-group vd (0..7)

    short8  kreg;
    ushort4 va, vc;

    #define LOAD_TILE(m0_) {                                                        \
        const int m0i = (m0_);                                                      \
        if (tid < 256) {                                                            \
            kreg = *reinterpret_cast<const short8*>(kb + (size_t)(m0i + kr) * C + h * DK + kc * 8); \
        } else {                                                                    \
            const ushort* v0 = vb + (size_t)(m0i + 2 * vp) * C + h * DK + vd * 4;   \
            va = *reinterpret_cast<const ushort4*>(v0);                             \
            vc = *reinterpret_cast<const ushort4*>(v0 + C);                         \
        }                                                                           \
    }

    LOAD_TILE(0);

    for (int t = 0; t < N / 64; ++t) {
        // ---- write staged tile to LDS
        if (tid < 256) {
            *reinterpret_cast<short8*>(Ks + kr * 40 + kc * 8) = kreg;
        } else {
            *reinterpret_cast<unsigned*>(Vt + (vd * 4 + 0) * 72 + 2 * vp) = (unsigned)va.x | ((unsigned)vc.x << 16);
            *reinterpret_cast<unsigned*>(Vt + (vd * 4 + 1) * 72 + 2 * vp) = (unsigned)va.y | ((unsigned)vc.y << 16);
            *reinterpret_cast<unsigned*>(Vt + (vd * 4 + 2) * 72 + 2 * vp) = (unsigned)va.z | ((unsigned)vc.z << 16);
            *reinterpret_cast<unsigned*>(Vt + (vd * 4 + 3) * 72 + 2 * vp) = (unsigned)va.w | ((unsigned)vc.w << 16);
        }
        __syncthreads();

        // ---- issue next tile's global loads (overlap with compute below)
        if (t < N / 64 - 1) LOAD_TILE((t + 1) * 64);

        // ---- QK^T (swapped): st[u][r] = S[key=16u+4g+r][q=lq]
        f32x4 st[4];
        __builtin_amdgcn_s_setprio(1);
        #pragma unroll
        for (int u = 0; u < 4; ++u) {
            short8 kf = *reinterpret_cast<const short8*>(Ks + (lq + 16 * u) * 40 + 8 * g);
            f32x4 z = {0.f, 0.f, 0.f, 0.f};
            st[u] = __builtin_amdgcn_mfma_f32_16x16x32_bf16(kf, qf, z, 0, 0, 0);
        }
        __builtin_amdgcn_s_setprio(0);

        // ---- online softmax, exp2 domain, defer-max
        float mxl = st[0][0];
        #pragma unroll
        for (int u = 0; u < 4; ++u)
            #pragma unroll
            for (int r = 0; r < 4; ++r) mxl = fmaxf(mxl, st[u][r]);

        if (!__all(mxl <= m + 8.0f)) {
            float mx = fmaxf(mxl, __shfl_xor(mxl, 16));
            mx = fmaxf(mx, __shfl_xor(mx, 32));
            float nm = fmaxf(m, mx);
            float corr = exp2f(m - nm);
            m = nm;
            lsum *= corr;
            float cw0 = __shfl(corr, 4 * g + 0);
            float cw1 = __shfl(corr, 4 * g + 1);
            float cw2 = __shfl(corr, 4 * g + 2);
            float cw3 = __shfl(corr, 4 * g + 3);
            acc0[0] *= cw0; acc0[1] *= cw1; acc0[2] *= cw2; acc0[3] *= cw3;
            acc1[0] *= cw0; acc1[1] *= cw1; acc1[2] *= cw2; acc1[3] *= cw3;
        }

        float ps = 0.f;
        uint2 pw[4];
        #pragma unroll
        for (int u = 0; u < 4; ++u) {
            float p0 = exp2f(st[u][0] - m);
            float p1 = exp2f(st[u][1] - m);
            float p2 = exp2f(st[u][2] - m);
            float p3 = exp2f(st[u][3] - m);
            ps += (p0 + p1) + (p2 + p3);
            pw[u].x = cvtpk(p0, p1);
            pw[u].y = cvtpk(p2, p3);
        }
        lsum += ps;

        #pragma unroll
        for (int u = 0; u < 4; ++u)
            *reinterpret_cast<uint2*>(Pl + lq * 72 + 4 * g + 16 * u) = pw[u];

        // ---- PV: O[q=4g+r][d=lq(+16)]
        short8 pf0 = *reinterpret_cast<const short8*>(Pl + lq * 72 + 8 * g);
        short8 pf1 = *reinterpret_cast<const short8*>(Pl + lq * 72 + 32 + 8 * g);
        __builtin_amdgcn_s_setprio(1);
        #pragma unroll
        for (int k2 = 0; k2 < 2; ++k2) {
            short8 pf = k2 ? pf1 : pf0;
            short8 vf0 = *reinterpret_cast<const short8*>(Vt + lq * 72 + 32 * k2 + 8 * g);
            short8 vf1 = *reinterpret_cast<const short8*>(Vt + (lq + 16) * 72 + 32 * k2 + 8 * g);
            acc0 = __builtin_amdgcn_mfma_f32_16x16x32_bf16(pf, vf0, acc0, 0, 0, 0);
            acc1 = __builtin_amdgcn_mfma_f32_16x16x32_bf16(pf, vf1, acc1, 0, 0, 0);
        }
        __builtin_amdgcn_s_setprio(0);
        __syncthreads();
    }

    // ---- epilogue: reduce lsum, normalize, transpose via LDS (Ost overlays
    // the now-dead Ks/Vt/P region; loop-end barrier already separates), add x.
    lsum += __shfl_xor(lsum, 16);
    lsum += __shfl_xor(lsum, 32);
    const float iv = 1.0f / lsum;
    float iw0 = __shfl(iv, 4 * g + 0);
    float iw1 = __shfl(iv, 4 * g + 1);
    float iw2 = __shfl(iv, 4 * g + 2);
    float iw3 = __shfl(iv, 4 * g + 3);

    Ost[(lq +  0) * 132 + wq * 16 + 4 * g + 0] = acc0[0] * iw0;
    Ost[(lq +  0) * 132 + wq * 16 + 4 * g + 1] = acc0[1] * iw1;
    Ost[(lq +  0) * 132 + wq * 16 + 4 * g + 2] = acc0[2] * iw2;
    Ost[(lq +  0) * 132 + wq * 16 + 4 * g + 3] = acc0[3] * iw3;
    Ost[(lq + 16) * 132 + wq * 16 + 4 * g + 0] = acc1[0] * iw0;
    Ost[(lq + 16) * 132 + wq * 16 + 4 * g + 1] = acc1[1] * iw1;
    Ost[(lq + 16) * 132 + wq * 16 + 4 * g + 2] = acc1[2] * iw2;
    Ost[(lq + 16) * 132 + wq * 16 + 4 * g + 3] = acc1[3] * iw3;
    __syncthreads();

    {
        const int d  = tid >> 4;          // 0..31
        const int nn = (tid & 15) * 8;    // 0..120
        const size_t go = ((size_t)b * C + h * DK + d) * (size_t)N + n0 + nn;
        float4 o1 = *reinterpret_cast<float4*>(Ost + d * 132 + nn);
        float4 o2 = *reinterpret_cast<float4*>(Ost + d * 132 + nn + 4);
        float4 x1 = *reinterpret_cast<const float4*>(x + go);
        float4 x2 = *reinterpret_cast<const float4*>(x + go + 4);
        *reinterpret_cast<float4*>(out + go)     = make_float4(o1.x + x1.x, o1.y + x1.y, o1.z + x1.z, o1.w + x1.w);
        *reinterpret_cast<float4*>(out + go + 4) = make_float4(o2.x + x2.x, o2.y + x2.y, o2.z + x2.z, o2.w + x2.w);
    }
}

extern "C" void kernel_launch(void* const* d_in, const int* in_sizes, int n_in,
                              void* d_out, int out_size, void* d_ws, size_t ws_size,
                              hipStream_t stream) {
    const float* x  = (const float*)d_in[0];
    const float* wq = (const float*)d_in[1];
    const float* wk = (const float*)d_in[2];
    const float* wv = (const float*)d_in[3];
    float* out = (float*)d_out;
    ushort* ws = (ushort*)d_ws;

    const size_t NC = (size_t)N * C;
    const size_t needFull = 3 * (size_t)B * NC * sizeof(ushort);   // 14.2 MB

    if (ws_size >= needFull) {
        proj_kernel<<<dim3(18 * 2, 3, B), 256, 0, stream>>>(
            x, wq, wk, wv, ws, -1, (size_t)B * NC, NC);
        attn_kernel<<<dim3(18 * NH * B), 512, 0, stream>>>(
            ws, x, out, -1, (size_t)B * NC, NC, 4);
    } else {
        // per-batch fallback (3.5 MB): proj_b -> attn_b serialized on stream
        for (int b = 0; b < B; ++b) {
            proj_kernel<<<dim3(18 * 2, 3, 1), 256, 0, stream>>>(
                x, wq, wk, wv, ws, b, NC, 0);
            attn_kernel<<<dim3(18 * NH), 512, 0, stream>>>(
                ws, x, out, b, NC, 0, 1);
        }
    }
}